// Round 3
// baseline (284.749 us; speedup 1.0000x reference)
//
#include <hip/hip_runtime.h>
#include <hip/hip_bf16.h>

#define B_ 8
#define N_ 2048
#define FIN 256
#define FOUT 64
#define BN_ (B_ * N_)
#define KSEG 256   // per-wave K segment; 8 waves cover N_=2048

typedef unsigned short ushort_t;
typedef unsigned int uint_t;
typedef unsigned long long u64_t;
typedef __attribute__((ext_vector_type(8))) __bf16 bf16x8;
typedef __attribute__((ext_vector_type(4))) float f32x4;

union U4B8 { uint4 u; bf16x8 b; };

// ---------------- K0: compress adj (int32 0/1) -> bitmask, pure streaming ----------------
// wave ww handles 4096 consecutive ints (= 2 rows). Lane reads adj[base+it*64+lane]
// (256B/wave coalesced); __ballot packs 64 ints -> u64; lane it keeps qword it;
// final write = 64 lanes x 8B = 512B contiguous. bits64[q] covers ints [q*64, q*64+64).
__global__ __launch_bounds__(256) void k0_bits(
    const int* __restrict__ adj, u64_t* __restrict__ bits64)
{
    const int t = threadIdx.x;
    const int lane = t & 63, wid = t >> 6;
    const int ww = blockIdx.x * 4 + wid;            // 8192 waves total
    const int* p = adj + (size_t)ww * 4096 + lane;
    u64_t myq = 0;
    #pragma unroll 16
    for (int it = 0; it < 64; ++it) {
        const int v = p[(size_t)it * 64];
        const u64_t bal = __ballot(v > 0);
        if (it == lane) myq = bal;
    }
    bits64[(size_t)ww * 64 + lane] = myq;
}

// ---------------- K1: Wh = h @ W ; e_src/e_dst ; WhT stored bf16 transposed ----------------
__global__ __launch_bounds__(256) void k1_proj(
    const float* __restrict__ h, const float* __restrict__ W,
    const float* __restrict__ a, ushort_t* __restrict__ WhTB,
    float* __restrict__ e_src, float* __restrict__ e_dst)
{
    const int t = threadIdx.x;
    const int lane = t & 63;
    const int w = t >> 6;
    const int gr = blockIdx.x * 16 + w * 4;  // global row (b*N+i), 4 rows per wave
    const int c = lane;
    const float* hrow = h + (size_t)gr * FIN;
    float v0 = 0.f, v1 = 0.f, v2 = 0.f, v3 = 0.f;
    for (int k = 0; k < FIN; k += 4) {
        const float4 h0 = *(const float4*)(hrow + k);
        const float4 h1 = *(const float4*)(hrow + FIN + k);
        const float4 h2 = *(const float4*)(hrow + 2 * FIN + k);
        const float4 h3 = *(const float4*)(hrow + 3 * FIN + k);
        const float w0 = W[(k + 0) * FOUT + c];
        const float w1 = W[(k + 1) * FOUT + c];
        const float w2 = W[(k + 2) * FOUT + c];
        const float w3 = W[(k + 3) * FOUT + c];
        v0 += h0.x * w0 + h0.y * w1 + h0.z * w2 + h0.w * w3;
        v1 += h1.x * w0 + h1.y * w1 + h1.z * w2 + h1.w * w3;
        v2 += h2.x * w0 + h2.y * w1 + h2.z * w2 + h2.w * w3;
        v3 += h3.x * w0 + h3.y * w1 + h3.z * w2 + h3.w * w3;
    }
    const float a1c = a[c], a2c = a[FOUT + c];
    float s10 = v0 * a1c, s11 = v1 * a1c, s12 = v2 * a1c, s13 = v3 * a1c;
    float s20 = v0 * a2c, s21 = v1 * a2c, s22 = v2 * a2c, s23 = v3 * a2c;
    for (int off = 32; off; off >>= 1) {
        s10 += __shfl_xor(s10, off); s11 += __shfl_xor(s11, off);
        s12 += __shfl_xor(s12, off); s13 += __shfl_xor(s13, off);
        s20 += __shfl_xor(s20, off); s21 += __shfl_xor(s21, off);
        s22 += __shfl_xor(s22, off); s23 += __shfl_xor(s23, off);
    }
    if (lane == 0) {
        *(float4*)(e_src + gr) = make_float4(s10, s11, s12, s13);
        *(float4*)(e_dst + gr) = make_float4(s20, s21, s22, s23);
    }
    const int b = gr >> 11, i = gr & (N_ - 1);
    ushort4 us;
    us.x = __builtin_bit_cast(unsigned short, (__bf16)v0);
    us.y = __builtin_bit_cast(unsigned short, (__bf16)v1);
    us.z = __builtin_bit_cast(unsigned short, (__bf16)v2);
    us.w = __builtin_bit_cast(unsigned short, (__bf16)v3);
    *(ushort4*)(WhTB + (size_t)(b * FOUT + c) * N_ + i) = us;
}

// ---------------- K3: fused attention+PV from bitmask, split-K within block ----------------
// grid = 1024 blocks of 512 thr (8 waves). Block tile = 16 rows; wave = K-segment 256.
// Masked scores come from the bitmask (32B/lane, L2); only L2-resident WhTB/e_dst remain.
__global__ __launch_bounds__(512, 4) void k3_attn(
    const uint_t* __restrict__ bits32, const ushort_t* __restrict__ WhTB,
    const float* __restrict__ e_src, const float* __restrict__ e_dst,
    float* __restrict__ out)
{
    __shared__ float red[8 * 16 * 68];   // [wid][row][68] pad: 2-way bank (free), 16B aligned
    __shared__ float sred[8 * 16];
    __shared__ float ssum[16];

    const int t = threadIdx.x;
    const int lane = t & 63, wid = t >> 6;
    const int l15 = lane & 15, g = lane >> 4;   // MFMA lane decomposition
    const int b = blockIdx.x & 7;               // XCD pin: batch -> one XCD's L2
    const int tile = blockIdx.x >> 3;
    const int i0 = tile * 16;
    const int jseg = wid * KSEG;

    const size_t row_g = (size_t)(b * N_ + i0 + l15);
    const float* edp = e_dst + b * N_ + jseg + g * 8;
    const ushort_t* wb = WhTB + (size_t)(b * FOUT + l15) * N_ + jseg + g * 8;
    const float es = e_src[row_g];

    // this lane's mask bits for the whole 256-wide segment: 8 dwords = 32B
    const uint_t* bitp = bits32 + row_g * (N_ / 32) + wid * 8;
    const uint4 qa = *(const uint4*)(bitp);
    const uint4 qb = *(const uint4*)(bitp + 4);
    const uint_t dmask[8] = {qa.x, qa.y, qa.z, qa.w, qb.x, qb.y, qb.z, qb.w};

    f32x4 acc[4];
    #pragma unroll
    for (int n = 0; n < 4; ++n)
        #pragma unroll
        for (int r = 0; r < 4; ++r) acc[n][r] = 0.f;
    float srow = 0.f;

    #pragma unroll
    for (int kc = 0; kc < KSEG; kc += 32) {
        const uint_t mbyte = (dmask[kc / 32] >> (g * 8)) & 0xffu;
        const float4 ed0 = *(const float4*)(edp + kc);
        const float4 ed1 = *(const float4*)(edp + kc + 4);
        const float ev[8] = {ed0.x, ed0.y, ed0.z, ed0.w, ed1.x, ed1.y, ed1.z, ed1.w};
        bf16x8 af;
        #pragma unroll
        for (int u = 0; u < 8; ++u) {
            float e = es + ev[u];
            e = fmaxf(e, 0.2f * e);            // leaky_relu
            const float p = (mbyte >> u) & 1u ? __expf(e) : 0.f;
            srow += p;
            af[u] = (__bf16)p;
        }
        #pragma unroll
        for (int n = 0; n < 4; ++n) {
            U4B8 bfr;
            bfr.u = *(const uint4*)(wb + (size_t)n * 16 * N_ + kc);
            acc[n] = __builtin_amdgcn_mfma_f32_16x16x32_bf16(af, bfr.b, acc[n], 0, 0, 0);
        }
    }

    // per-row partial sums: lane holds k-subset of row l15 -> reduce over g
    srow += __shfl_xor(srow, 16);
    srow += __shfl_xor(srow, 32);
    if (lane < 16) sred[wid * 16 + lane] = srow;

    // C layout: col = n*16 + l15, row = g*4 + r
    #pragma unroll
    for (int n = 0; n < 4; ++n)
        #pragma unroll
        for (int r = 0; r < 4; ++r)
            red[(wid * 16 + g * 4 + r) * 68 + n * 16 + l15] = acc[n][r];
    __syncthreads();

    if (t < 16) {
        float s = 0.f;
        #pragma unroll
        for (int w = 0; w < 8; ++w) s += sred[w * 16 + t];
        ssum[t] = 1.0f / s;
    }
    const int row = t >> 4, c4 = (t & 15) * 4;
    float4 v = make_float4(0.f, 0.f, 0.f, 0.f);
    if (t < 256) {
        #pragma unroll
        for (int w = 0; w < 8; ++w) {
            const float4 u = *(const float4*)&red[(w * 16 + row) * 68 + c4];
            v.x += u.x; v.y += u.y; v.z += u.z; v.w += u.w;
        }
    }
    __syncthreads();
    if (t < 256) {
        const float rs = ssum[row];
        float4 o; float x;
        x = v.x * rs; o.x = x > 0.f ? x : __expf(x) - 1.f;
        x = v.y * rs; o.y = x > 0.f ? x : __expf(x) - 1.f;
        x = v.z * rs; o.z = x > 0.f ? x : __expf(x) - 1.f;
        x = v.w * rs; o.w = x > 0.f ? x : __expf(x) - 1.f;
        *(float4*)(out + ((size_t)(b * N_ + i0 + row)) * FOUT + c4) = o;
    }
}

extern "C" void kernel_launch(void* const* d_in, const int* in_sizes, int n_in,
                              void* d_out, int out_size, void* d_ws, size_t ws_size,
                              hipStream_t stream) {
    const float* h = (const float*)d_in[0];
    const int* adj = (const int*)d_in[1];
    const float* W = (const float*)d_in[2];
    const float* a = (const float*)d_in[3];
    float* out = (float*)d_out;

    // ws layout: WhTB bf16 2MB | e_src 64KB | e_dst 64KB | bits 4.2MB
    char* ws = (char*)d_ws;
    ushort_t* WhTB = (ushort_t*)ws;
    float* e_src = (float*)(ws + 2 * 1024 * 1024);
    float* e_dst = e_src + BN_;
    u64_t* bits = (u64_t*)(e_dst + BN_);

    k0_bits<<<2048, 256, 0, stream>>>(adj, bits);
    k1_proj<<<BN_ / 16, 256, 0, stream>>>(h, W, a, WhTB, e_src, e_dst);
    k3_attn<<<BN_ / 16, 512, 0, stream>>>((const uint_t*)bits, WhTB, e_src, e_dst, out);
}

// Round 6
// 272.481 us; speedup vs baseline: 1.0450x; 1.0450x over previous
//
#include <hip/hip_runtime.h>
#include <hip/hip_bf16.h>

#define B_ 8
#define N_ 2048
#define FIN 256
#define FOUT 64
#define BN_ (B_ * N_)
#define KSEG 256   // per-wave K segment; 8 waves cover N_=2048

typedef unsigned short ushort_t;
typedef __attribute__((ext_vector_type(8))) __bf16 bf16x8;
typedef __attribute__((ext_vector_type(4))) float f32x4;
typedef __attribute__((ext_vector_type(4))) int i32x4;   // clang vector: OK for nontemporal builtins

union U4B8 { uint4 u; bf16x8 b; };

// ---------------- K1: Wh = h @ W ; e_src/e_dst ; WhT stored bf16 transposed ----------------
// block = 256 thr = 4 waves; each wave: 4 consecutive rows, lane = output col c.
// WhTB writes go through an LDS transpose so each c-row emits one 32B-contiguous run.
__global__ __launch_bounds__(256) void k1_proj(
    const float* __restrict__ h, const float* __restrict__ W,
    const float* __restrict__ a, ushort_t* __restrict__ WhTB,
    float* __restrict__ e_src, float* __restrict__ e_dst)
{
    __shared__ ushort_t wh_s[64][18];        // [c][16 rows + pad]
    const int t = threadIdx.x;
    const int lane = t & 63;
    const int w = t >> 6;
    const int gr = blockIdx.x * 16 + w * 4;  // global row (b*N+i), 4 rows per wave
    const int c = lane;
    const float* hrow = h + (size_t)gr * FIN;
    float v0 = 0.f, v1 = 0.f, v2 = 0.f, v3 = 0.f;
    for (int k = 0; k < FIN; k += 4) {
        const float4 h0 = *(const float4*)(hrow + k);
        const float4 h1 = *(const float4*)(hrow + FIN + k);
        const float4 h2 = *(const float4*)(hrow + 2 * FIN + k);
        const float4 h3 = *(const float4*)(hrow + 3 * FIN + k);
        const float w0 = W[(k + 0) * FOUT + c];
        const float w1 = W[(k + 1) * FOUT + c];
        const float w2 = W[(k + 2) * FOUT + c];
        const float w3 = W[(k + 3) * FOUT + c];
        v0 += h0.x * w0 + h0.y * w1 + h0.z * w2 + h0.w * w3;
        v1 += h1.x * w0 + h1.y * w1 + h1.z * w2 + h1.w * w3;
        v2 += h2.x * w0 + h2.y * w1 + h2.z * w2 + h2.w * w3;
        v3 += h3.x * w0 + h3.y * w1 + h3.z * w2 + h3.w * w3;
    }
    // e_src/e_dst wave reductions over c
    const float a1c = a[c], a2c = a[FOUT + c];
    float s10 = v0 * a1c, s11 = v1 * a1c, s12 = v2 * a1c, s13 = v3 * a1c;
    float s20 = v0 * a2c, s21 = v1 * a2c, s22 = v2 * a2c, s23 = v3 * a2c;
    for (int off = 32; off; off >>= 1) {
        s10 += __shfl_xor(s10, off); s11 += __shfl_xor(s11, off);
        s12 += __shfl_xor(s12, off); s13 += __shfl_xor(s13, off);
        s20 += __shfl_xor(s20, off); s21 += __shfl_xor(s21, off);
        s22 += __shfl_xor(s22, off); s23 += __shfl_xor(s23, off);
    }
    if (lane == 0) {
        *(float4*)(e_src + gr) = make_float4(s10, s11, s12, s13);
        *(float4*)(e_dst + gr) = make_float4(s20, s21, s22, s23);
    }
    // transpose in LDS, then 32B-contiguous stores along i
    wh_s[c][w * 4 + 0] = __builtin_bit_cast(ushort_t, (__bf16)v0);
    wh_s[c][w * 4 + 1] = __builtin_bit_cast(ushort_t, (__bf16)v1);
    wh_s[c][w * 4 + 2] = __builtin_bit_cast(ushort_t, (__bf16)v2);
    wh_s[c][w * 4 + 3] = __builtin_bit_cast(ushort_t, (__bf16)v3);
    __syncthreads();
    const int b = (blockIdx.x * 16) >> 11, i0 = (blockIdx.x * 16) & (N_ - 1);
    if (t < 128) {
        const int cc = t >> 1, half = t & 1;
        ushort4 us;
        us.x = wh_s[cc][half * 8 + 0]; us.y = wh_s[cc][half * 8 + 1];
        us.z = wh_s[cc][half * 8 + 2]; us.w = wh_s[cc][half * 8 + 3];
        ushort4 us2;
        us2.x = wh_s[cc][half * 8 + 4]; us2.y = wh_s[cc][half * 8 + 5];
        us2.z = wh_s[cc][half * 8 + 6]; us2.w = wh_s[cc][half * 8 + 7];
        ushort_t* dst = WhTB + (size_t)(b * FOUT + cc) * N_ + i0 + half * 8;
        *(ushort4*)(dst) = us;
        *(ushort4*)(dst + 4) = us2;
    }
}

// ---------------- K3: fused attention+PV, split-K within block ----------------
// grid = 1024 blocks of 512 thr (8 waves). Block tile = 16 rows; wave = K-segment 256.
// b = bid & 7 pins each batch to one XCD so WhTB[b] (2 MB) stays L2-resident.
// adj loads are nontemporal (streamed once) to avoid evicting WhTB from L2.
__global__ __launch_bounds__(512, 4) void k3_attn(
    const int* __restrict__ adj, const ushort_t* __restrict__ WhTB,
    const float* __restrict__ e_src, const float* __restrict__ e_dst,
    float* __restrict__ out)
{
    __shared__ float red[8 * 16 * 68];   // [wid][row][68] pad: 2-way bank (free), 16B aligned
    __shared__ float edl[N_];            // e_dst[b] staged (8KB), broadcast reads
    __shared__ float sred[8 * 16];
    __shared__ float ssum[16];

    const int t = threadIdx.x;
    const int lane = t & 63, wid = t >> 6;
    const int l15 = lane & 15, g = lane >> 4;   // MFMA lane decomposition
    const int b = blockIdx.x & 7;               // XCD pin
    const int tile = blockIdx.x >> 3;
    const int i0 = tile * 16;
    const int jseg = wid * KSEG;

    *(float4*)(&edl[t * 4]) = *(const float4*)(e_dst + b * N_ + t * 4);

    const size_t row_g = (size_t)(b * N_ + i0 + l15);
    const int* arow = adj + row_g * N_ + jseg + g * 8;
    const ushort_t* wb = WhTB + (size_t)(b * FOUT + l15) * N_ + jseg + g * 8;
    const float es = e_src[row_g];

    f32x4 acc[4];
    #pragma unroll
    for (int n = 0; n < 4; ++n)
        #pragma unroll
        for (int r = 0; r < 4; ++r) acc[n][r] = 0.f;
    float srow = 0.f;

    // register double-buffer prefetch of adj (HBM-latency hiding); nt = stream past L2
    i32x4 c0 = __builtin_nontemporal_load((const i32x4*)(arow));
    i32x4 c1 = __builtin_nontemporal_load((const i32x4*)(arow + 4));
    __syncthreads();   // edl ready

    #pragma unroll
    for (int kc = 0; kc < KSEG; kc += 32) {
        i32x4 p0, p1;
        if (kc + 32 < KSEG) {
            p0 = __builtin_nontemporal_load((const i32x4*)(arow + kc + 32));
            p1 = __builtin_nontemporal_load((const i32x4*)(arow + kc + 36));
        } else { p0 = c0; p1 = c1; }
        const float* edp = &edl[jseg + kc + g * 8];
        const float4 ed0 = *(const float4*)(edp);
        const float4 ed1 = *(const float4*)(edp + 4);
        const float ev[8] = {ed0.x, ed0.y, ed0.z, ed0.w, ed1.x, ed1.y, ed1.z, ed1.w};
        const int aa[8] = {c0.x, c0.y, c0.z, c0.w, c1.x, c1.y, c1.z, c1.w};
        bf16x8 af;
        #pragma unroll
        for (int u = 0; u < 8; ++u) {
            float e = es + ev[u];
            e = fmaxf(e, 0.2f * e);            // leaky_relu
            const float p = aa[u] > 0 ? __expf(e) : 0.f;
            srow += p;
            af[u] = (__bf16)p;
        }
        #pragma unroll
        for (int n = 0; n < 4; ++n) {
            U4B8 bfr;
            bfr.u = *(const uint4*)(wb + (size_t)n * 16 * N_ + kc);
            acc[n] = __builtin_amdgcn_mfma_f32_16x16x32_bf16(af, bfr.b, acc[n], 0, 0, 0);
        }
        c0 = p0; c1 = p1;
    }

    // per-row partial sums: lane holds k-subset of row l15 -> reduce over g
    srow += __shfl_xor(srow, 16);
    srow += __shfl_xor(srow, 32);
    if (lane < 16) sred[wid * 16 + lane] = srow;

    // C layout: col = n*16 + l15, row = g*4 + r
    #pragma unroll
    for (int n = 0; n < 4; ++n)
        #pragma unroll
        for (int r = 0; r < 4; ++r)
            red[(wid * 16 + g * 4 + r) * 68 + n * 16 + l15] = acc[n][r];
    __syncthreads();

    if (t < 16) {
        float s = 0.f;
        #pragma unroll
        for (int w = 0; w < 8; ++w) s += sred[w * 16 + t];
        ssum[t] = 1.0f / s;
    }
    const int row = t >> 4, c4 = (t & 15) * 4;
    float4 v = make_float4(0.f, 0.f, 0.f, 0.f);
    if (t < 256) {
        #pragma unroll
        for (int w = 0; w < 8; ++w) {
            const float4 u = *(const float4*)&red[(w * 16 + row) * 68 + c4];
            v.x += u.x; v.y += u.y; v.z += u.z; v.w += u.w;
        }
    }
    __syncthreads();
    if (t < 256) {
        const float rs = ssum[row];
        float4 o; float x;
        x = v.x * rs; o.x = x > 0.f ? x : __expf(x) - 1.f;
        x = v.y * rs; o.y = x > 0.f ? x : __expf(x) - 1.f;
        x = v.z * rs; o.z = x > 0.f ? x : __expf(x) - 1.f;
        x = v.w * rs; o.w = x > 0.f ? x : __expf(x) - 1.f;
        *(float4*)(out + ((size_t)(b * N_ + i0 + row)) * FOUT + c4) = o;
    }
}

extern "C" void kernel_launch(void* const* d_in, const int* in_sizes, int n_in,
                              void* d_out, int out_size, void* d_ws, size_t ws_size,
                              hipStream_t stream) {
    const float* h = (const float*)d_in[0];
    const int* adj = (const int*)d_in[1];
    const float* W = (const float*)d_in[2];
    const float* a = (const float*)d_in[3];
    float* out = (float*)d_out;

    // ws layout: WhTB bf16 2MB | e_src 64KB | e_dst 64KB
    char* ws = (char*)d_ws;
    ushort_t* WhTB = (ushort_t*)ws;
    float* e_src = (float*)(ws + 2 * 1024 * 1024);
    float* e_dst = e_src + BN_;

    k1_proj<<<BN_ / 16, 256, 0, stream>>>(h, W, a, WhTB, e_src, e_dst);
    k3_attn<<<BN_ / 16, 512, 0, stream>>>(adj, WhTB, e_src, e_dst, out);
}